// Round 8
// baseline (478.171 us; speedup 1.0000x reference)
//
#include <hip/hip_runtime.h>
#include <cfloat>

// Problem constants
#define B_   16
#define C_   256
#define HW_  4096      // 64*64
#define N_   65536     // B_*HW_
#define K_   1024

// Output layout (float32, concatenated flat in return order):
//  [0] loss | [1,+16777216) quantized (b c h w) | [16777217] perplexity
//  [16777218,+67108864) encodings (N,K)
#define OUT_QOFF   1
#define OUT_POFF   16777217
#define OUT_EOFF   16777218

#define MARGIN 0.6f

typedef __bf16 bf16x8 __attribute__((ext_vector_type(8)));
typedef float  f32x4  __attribute__((ext_vector_type(4)));

// ---------------------------------------------------------------- bf16 round
__device__ inline ushort f2bf(float f) {
    union { float f; unsigned u; } a; a.f = f;
    unsigned u = a.u;
    unsigned r = (u + 0x7fffu + ((u >> 16) & 1u)) >> 16;   // RNE
    return (ushort)r;
}

// --------------------------- prep: pack eh (bf16) + enorm + zero counts/amb
// Packed layout per step s in [0,64): s = (k>>5)*2 + (c>>7); within 8192-B
// block: [cg(16)][code(32)][ci(8)] bf16.
__global__ __launch_bounds__(256) void k_prep(const float* __restrict__ emb,
                                              char* __restrict__ epk,
                                              float* __restrict__ enorm,
                                              int* __restrict__ counts,
                                              int* __restrict__ ambCount) {
    const int k = blockIdx.x;
    const int c = threadIdx.x;
    float v = emb[k * C_ + c];
    int s  = (k >> 5) * 2 + (c >> 7);
    int cl = c & 127;
    size_t off = (size_t)s * 8192 + (size_t)((cl >> 3) * 512 + (k & 31) * 16 + (cl & 7) * 2);
    *(ushort*)(epk + off) = f2bf(v);
    float sq = v * v;
    __shared__ float red[4];
#pragma unroll
    for (int o = 32; o > 0; o >>= 1) sq += __shfl_down(sq, o);
    if ((c & 63) == 0) red[c >> 6] = sq;
    __syncthreads();
    if (c == 0) {
        enorm[k]  = (red[0] + red[1]) + (red[2] + red[3]);
        counts[k] = 0;
        if (k == 0) *ambCount = 0;
    }
}

// ---------------------------------------------------- transpose emb -> embT
__global__ __launch_bounds__(256) void k_transpose(const float* __restrict__ emb,
                                                   float* __restrict__ embT) {
    int i = blockIdx.x * 256 + threadIdx.x;   // i = k*C + c (coalesced read)
    int k = i >> 8, c = i & 255;
    embT[c * K_ + k] = emb[i];
}

// ------------------------------------------- pass 1: bf16 screen (1 product)
// Block: 128 rows x 1024 codes, 4 waves (32 rows = 2 row-frags of 16 each).
// A = bf16(x) in regs; B = bf16(e) double-buffered in LDS. Streaming top-2
// distances (+ best index) per lane; rows whose top-2 gap <= MARGIN go to the
// ambiguous list for exact refine; others are decided here.
__global__ __launch_bounds__(256, 2) void k_argmin_mfma(const float* __restrict__ x,
                                                        const char* __restrict__ epk,
                                                        const float* __restrict__ enorm,
                                                        int* __restrict__ bestIdx,
                                                        int* __restrict__ counts,
                                                        int* __restrict__ ambCount,
                                                        int* __restrict__ ambList) {
    __shared__ __align__(16) char Bs[2][8192];
    __shared__ float En[K_];

    const int tid  = threadIdx.x;
    const int lane = tid & 63;
    const int wid  = tid >> 6;
    const int l15  = lane & 15;
    const int kg   = lane >> 4;
    const int row0 = blockIdx.x * 128;
    const int cpOff = wid * 1024 + lane * 16;

    for (int i = tid; i < K_; i += 256) En[i] = enorm[i];

    // ---- A fragments (bf16 once): frag f rows = wid*32+f*16+l15, k = kg*8+i
    union FU { bf16x8 v; ushort u[8]; };
    FU Ah[2][8];
#pragma unroll
    for (int f = 0; f < 2; ++f) {
        const int n  = row0 + wid * 32 + f * 16 + l15;
        const int b  = n >> 12, hw = n & 4095;
        const float* xb = x + (size_t)b * (C_ * HW_) + hw;
#pragma unroll
        for (int cb = 0; cb < 8; ++cb) {
#pragma unroll
            for (int i = 0; i < 8; ++i)
                Ah[f][cb].u[i] = f2bf(xb[(cb * 32 + kg * 8 + i) * HW_]);
        }
    }
    __syncthreads();

    // ---- stage step 0
    {
        const char* src = epk + (size_t)cpOff;
        char* dstb = &Bs[0][0] + cpOff;
#pragma unroll
        for (int j = 0; j < 2; ++j) {
            __builtin_amdgcn_global_load_lds(
                (const __attribute__((address_space(1))) void*)(src + j * 4096),
                (__attribute__((address_space(3))) void*)(dstb + j * 4096), 16, 0, 0);
        }
    }

    // slots t = f*4 + r
    float bd[8], sd[8];
    int   bi[8];
#pragma unroll
    for (int t = 0; t < 8; ++t) { bd[t] = FLT_MAX; sd[t] = FLT_MAX; bi[t] = 0; }
    const int laneB = kg * 512 + l15 * 16;
    const f32x4 zero = {0.f, 0.f, 0.f, 0.f};
    f32x4 accA0, accB0, accA1, accB1;

#define STEP(H, IS_LAST) do {                                                       \
    if (!(IS_LAST)) {                                                               \
        int sn = 2 * kt + (H) + 1;                                                  \
        const char* src = epk + (size_t)sn * 8192 + (size_t)cpOff;                  \
        char* dstb = &Bs[1 - (H)][0] + cpOff;                                       \
        _Pragma("unroll")                                                           \
        for (int j = 0; j < 2; ++j) {                                               \
            __builtin_amdgcn_global_load_lds(                                       \
                (const __attribute__((address_space(1))) void*)(src + j * 4096),    \
                (__attribute__((address_space(3))) void*)(dstb + j * 4096),         \
                16, 0, 0);                                                          \
        }                                                                           \
        asm volatile("s_waitcnt vmcnt(2)" ::: "memory");                            \
    } else {                                                                        \
        asm volatile("s_waitcnt vmcnt(0)" ::: "memory");                            \
    }                                                                               \
    __builtin_amdgcn_s_barrier();                                                   \
    asm volatile("" ::: "memory");                                                  \
    {                                                                               \
        const char* bbase = &Bs[(H)][0] + laneB;                                    \
        _Pragma("unroll")                                                           \
        for (int cbl = 0; cbl < 4; ++cbl) {                                         \
            const char* bp = bbase + cbl * 2048;                                    \
            bf16x8 Bh0 = *(const bf16x8*)(bp);                                      \
            bf16x8 Bh1 = *(const bf16x8*)(bp + 256);                                \
            const bf16x8 a0h = Ah[0][(H) * 4 + cbl].v;                              \
            const bf16x8 a1h = Ah[1][(H) * 4 + cbl].v;                              \
            accA0 = __builtin_amdgcn_mfma_f32_16x16x32_bf16(a0h, Bh0, accA0, 0,0,0);\
            accB0 = __builtin_amdgcn_mfma_f32_16x16x32_bf16(a0h, Bh1, accB0, 0,0,0);\
            accA1 = __builtin_amdgcn_mfma_f32_16x16x32_bf16(a1h, Bh0, accA1, 0,0,0);\
            accB1 = __builtin_amdgcn_mfma_f32_16x16x32_bf16(a1h, Bh1, accB1, 0,0,0);\
        }                                                                           \
    }                                                                               \
    asm volatile("s_waitcnt lgkmcnt(0)" ::: "memory");                              \
    __builtin_amdgcn_s_barrier();                                                   \
} while (0)

// streaming top-2 over a pair of entries (dA at col cA_ < dB at col cB_):
// new best (index tracked, first-occurrence), new 2nd-best distance.
#define UPD2(dA_, cA_, dB_, cB_, t_) do {                                           \
    float dA = (dA_), dB = (dB_);                                                   \
    float med = __builtin_amdgcn_fmed3f(bd[t_], dA, dB);                            \
    sd[t_] = fminf(sd[t_], med);                                                    \
    bool tA = dA < bd[t_];                                                          \
    float b1 = tA ? dA : bd[t_];                                                    \
    int   i1 = tA ? (cA_) : bi[t_];                                                 \
    bool tB = dB < b1;                                                              \
    bd[t_] = tB ? dB : b1;                                                          \
    bi[t_] = tB ? (cB_) : i1;                                                       \
} while (0)

    for (int kt = 0; kt < 32; ++kt) {
        accA0 = zero; accB0 = zero; accA1 = zero; accB1 = zero;
        STEP(0, false);
        STEP(1, kt == 31);
        const int cA = kt * 32 + l15;
        const int cB = cA + 16;
        const float enA = En[cA], enB = En[cB];
#pragma unroll
        for (int r = 0; r < 4; ++r) {
            UPD2(fmaf(-2.0f, accA0[r], enA), cA, fmaf(-2.0f, accB0[r], enB), cB, r);
            UPD2(fmaf(-2.0f, accA1[r], enA), cA, fmaf(-2.0f, accB1[r], enB), cB, 4 + r);
        }
    }
#undef STEP
#undef UPD2

    // cross-lane top-2 merge over the 16 col-lanes; decide or defer
#pragma unroll
    for (int t = 0; t < 8; ++t) {
        float bd_ = bd[t]; int bi_ = bi[t]; float sd_ = sd[t];
#pragma unroll
        for (int m = 1; m < 16; m <<= 1) {
            float obd = __shfl_xor(bd_, m);
            int   obi = __shfl_xor(bi_, m);
            float osd = __shfl_xor(sd_, m);
            float mx = fmaxf(bd_, obd);
            sd_ = fminf(fminf(sd_, osd), mx);
            bool take = (obd < bd_) || (obd == bd_ && obi < bi_);
            bd_ = take ? obd : bd_;
            bi_ = take ? obi : bi_;
        }
        if (l15 == 0) {
            const int f = t >> 2, r = t & 3;
            const int n = row0 + wid * 32 + f * 16 + kg * 4 + r;
            if (sd_ <= bd_ + MARGIN) {
                int p = atomicAdd(ambCount, 1);
                ambList[p] = n;
            } else {
                bestIdx[n] = bi_;
                atomicAdd(&counts[bi_], 1);
            }
        }
    }
}

// --------------------- pass 2: exact fp32 full re-search of ambiguous rows
// One wave per row; lane owns 16 consecutive codes; channels processed in
// ascending order (deterministic); first-occurrence argmin.
__global__ __launch_bounds__(256) void k_refine(const float* __restrict__ x,
                                                const float* __restrict__ embT,
                                                const float* __restrict__ enorm,
                                                const int* __restrict__ ambCount,
                                                const int* __restrict__ ambList,
                                                int* __restrict__ bestIdx,
                                                int* __restrict__ counts) {
    const int tid  = threadIdx.x;
    const int lane = tid & 63;
    const int wid  = tid >> 6;
    const int wg   = blockIdx.x * 4 + wid;   // 256 blocks * 4 waves = 1024
    const int total = *ambCount;

    for (int w = wg; w < total; w += 1024) {
        const int n = ambList[w];
        const int b = n >> 12, hw = n & 4095;
        const float* xb = x + (size_t)b * (C_ * HW_) + hw;
        float xr0 = xb[(lane * 4 + 0) * HW_];
        float xr1 = xb[(lane * 4 + 1) * HW_];
        float xr2 = xb[(lane * 4 + 2) * HW_];
        float xr3 = xb[(lane * 4 + 3) * HW_];
        f32x4 a0 = {0.f,0.f,0.f,0.f}, a1 = a0, a2 = a0, a3 = a0;
        const float* bt = embT + lane * 16;
        for (int cq = 0; cq < 64; ++cq) {
            float xc0 = __shfl(xr0, cq);
            float xc1 = __shfl(xr1, cq);
            float xc2 = __shfl(xr2, cq);
            float xc3 = __shfl(xr3, cq);
            const float* br = bt + (size_t)(cq * 4) * K_;
#pragma unroll
            for (int j = 0; j < 1; ++j) { /* keep order: c ascending */ }
            {
                f32x4 e0 = *(const f32x4*)(br + 0), e1 = *(const f32x4*)(br + 4);
                f32x4 e2 = *(const f32x4*)(br + 8), e3 = *(const f32x4*)(br + 12);
                a0 += xc0 * e0; a1 += xc0 * e1; a2 += xc0 * e2; a3 += xc0 * e3;
            }
            {
                const float* b1p = br + K_;
                f32x4 e0 = *(const f32x4*)(b1p + 0), e1 = *(const f32x4*)(b1p + 4);
                f32x4 e2 = *(const f32x4*)(b1p + 8), e3 = *(const f32x4*)(b1p + 12);
                a0 += xc1 * e0; a1 += xc1 * e1; a2 += xc1 * e2; a3 += xc1 * e3;
            }
            {
                const float* b2p = br + 2 * K_;
                f32x4 e0 = *(const f32x4*)(b2p + 0), e1 = *(const f32x4*)(b2p + 4);
                f32x4 e2 = *(const f32x4*)(b2p + 8), e3 = *(const f32x4*)(b2p + 12);
                a0 += xc2 * e0; a1 += xc2 * e1; a2 += xc2 * e2; a3 += xc2 * e3;
            }
            {
                const float* b3p = br + 3 * K_;
                f32x4 e0 = *(const f32x4*)(b3p + 0), e1 = *(const f32x4*)(b3p + 4);
                f32x4 e2 = *(const f32x4*)(b3p + 8), e3 = *(const f32x4*)(b3p + 12);
                a0 += xc3 * e0; a1 += xc3 * e1; a2 += xc3 * e2; a3 += xc3 * e3;
            }
        }
        // distances + local argmin (ascending k => first occurrence)
        float bd = FLT_MAX; int bi = 0;
        const float* en = enorm + lane * 16;
        {
            f32x4 env = *(const f32x4*)(en + 0);
#pragma unroll
            for (int e = 0; e < 4; ++e) {
                float d = fmaf(-2.f, a0[e], env[e]);
                if (d < bd) { bd = d; bi = lane * 16 + e; }
            }
        }
        {
            f32x4 env = *(const f32x4*)(en + 4);
#pragma unroll
            for (int e = 0; e < 4; ++e) {
                float d = fmaf(-2.f, a1[e], env[e]);
                if (d < bd) { bd = d; bi = lane * 16 + 4 + e; }
            }
        }
        {
            f32x4 env = *(const f32x4*)(en + 8);
#pragma unroll
            for (int e = 0; e < 4; ++e) {
                float d = fmaf(-2.f, a2[e], env[e]);
                if (d < bd) { bd = d; bi = lane * 16 + 8 + e; }
            }
        }
        {
            f32x4 env = *(const f32x4*)(en + 12);
#pragma unroll
            for (int e = 0; e < 4; ++e) {
                float d = fmaf(-2.f, a3[e], env[e]);
                if (d < bd) { bd = d; bi = lane * 16 + 12 + e; }
            }
        }
#pragma unroll
        for (int m = 1; m < 64; m <<= 1) {
            float od = __shfl_xor(bd, m);
            int   oi = __shfl_xor(bi, m);
            if (od < bd || (od == bd && oi < bi)) { bd = od; bi = oi; }
        }
        if (lane == 0) {
            bestIdx[n] = bi;
            atomicAdd(&counts[bi], 1);
        }
    }
}

// --------------------------------------------- gather quantized + loss part
__global__ __launch_bounds__(256) void k_quant(const float* __restrict__ x,
                                               const float* __restrict__ emb,
                                               const int* __restrict__ bestIdx,
                                               float* __restrict__ outq,
                                               float* __restrict__ partials) {
    const int tid = threadIdx.x;
    float lsum = 0.f;
#pragma unroll
    for (int it = 0; it < 4; ++it) {
        int q  = blockIdx.x * 256 + tid + it * (4096 * 256);
        int f  = q << 2;
        int hw = f & 4095;
        int c  = (f >> 12) & 255;
        int b  = f >> 20;
        int n0 = (b << 12) + hw;
        int4  id = *(const int4*)&bestIdx[n0];
        float4 xv = *(const float4*)&x[f];
        float q0 = emb[id.x * C_ + c];
        float q1 = emb[id.y * C_ + c];
        float q2 = emb[id.z * C_ + c];
        float q3 = emb[id.w * C_ + c];
        f32x4 ov;
        ov.x = xv.x + (q0 - xv.x);
        ov.y = xv.y + (q1 - xv.y);
        ov.z = xv.z + (q2 - xv.z);
        ov.w = xv.w + (q3 - xv.w);
        __builtin_nontemporal_store(ov, (f32x4*)&outq[f]);
        float d0 = q0 - xv.x, d1 = q1 - xv.y, d2 = q2 - xv.z, d3 = q3 - xv.w;
        lsum += d0 * d0 + d1 * d1 + d2 * d2 + d3 * d3;
    }
    __shared__ float red[4];
#pragma unroll
    for (int o = 32; o > 0; o >>= 1) lsum += __shfl_down(lsum, o);
    if ((tid & 63) == 0) red[tid >> 6] = lsum;
    __syncthreads();
    if (tid == 0) partials[blockIdx.x] = (red[0] + red[1]) + (red[2] + red[3]);
}

// ------------------------------------------------------- one-hot encodings
__global__ __launch_bounds__(256) void k_enc(const int* __restrict__ bestIdx,
                                             float* __restrict__ enc) {
    const int k4 = threadIdx.x * 4;
    int row = blockIdx.x * 8;
#pragma unroll
    for (int j = 0; j < 8; ++j, ++row) {
        int idv = bestIdx[row];
        f32x4 v;
        v.x = (k4 + 0 == idv) ? 1.0f : 0.0f;
        v.y = (k4 + 1 == idv) ? 1.0f : 0.0f;
        v.z = (k4 + 2 == idv) ? 1.0f : 0.0f;
        v.w = (k4 + 3 == idv) ? 1.0f : 0.0f;
        __builtin_nontemporal_store(v, (f32x4*)&enc[(size_t)row * K_ + k4]);
    }
}

// ----------------------------------------------------------------- finalize
__global__ __launch_bounds__(256) void k_final(const float* __restrict__ partials,
                                               const int* __restrict__ counts,
                                               float* __restrict__ out) {
    const int tid = threadIdx.x;
    float s = 0.f;
    for (int i = tid; i < 4096; i += 256) s += partials[i];
    float h = 0.f;
    for (int k = tid; k < K_; k += 256) {
        float p = (float)counts[k] * (1.0f / 65536.0f);
        h += p * logf(p + 1e-10f);
    }
    __shared__ float redS[4], redH[4];
#pragma unroll
    for (int o = 32; o > 0; o >>= 1) {
        s += __shfl_down(s, o);
        h += __shfl_down(h, o);
    }
    if ((tid & 63) == 0) { redS[tid >> 6] = s; redH[tid >> 6] = h; }
    __syncthreads();
    if (tid == 0) {
        float S = (redS[0] + redS[1]) + (redS[2] + redS[3]);
        float H = (redH[0] + redH[1]) + (redH[2] + redH[3]);
        out[0]        = 0.25f * S / 16777216.0f;
        out[OUT_POFF] = expf(-H);
    }
}

extern "C" void kernel_launch(void* const* d_in, const int* in_sizes, int n_in,
                              void* d_out, int out_size, void* d_ws, size_t ws_size,
                              hipStream_t stream) {
    const float* x   = (const float*)d_in[0];
    const float* emb = (const float*)d_in[1];
    float* out = (float*)d_out;
    char*  ws  = (char*)d_ws;

    // Workspace layout
    int*   bestIdx  = (int*)(ws);                 // 262144 B
    int*   counts   = (int*)(ws + 262144);        //   4096 B
    float* partials = (float*)(ws + 266240);      //  16384 B
    float* enorm    = (float*)(ws + 282624);      //   4096 B
    int*   ambCount = (int*)(ws + 286720);        //   4096 B (pad)
    char*  epk      = ws + 290816;                // 524288 B packed eh (bf16)
    float* embT     = (float*)(ws + 815104);      // 1048576 B transposed codebook
    // ambiguous-row list lives in the (later overwritten) encodings region
    int* ambList = (int*)(out + OUT_EOFF);

    k_prep       <<<K_,       256, 0, stream>>>(emb, epk, enorm, counts, ambCount);
    k_transpose  <<<K_ * C_ / 256, 256, 0, stream>>>(emb, embT);
    k_argmin_mfma<<<N_ / 128, 256, 0, stream>>>(x, epk, enorm, bestIdx, counts,
                                                ambCount, ambList);
    k_refine     <<<256,      256, 0, stream>>>(x, embT, enorm, ambCount, ambList,
                                                bestIdx, counts);
    k_quant      <<<4096,     256, 0, stream>>>(x, emb, bestIdx, out + OUT_QOFF, partials);
    k_enc        <<<8192,     256, 0, stream>>>(bestIdx, out + OUT_EOFF);
    k_final      <<<1,        256, 0, stream>>>(partials, counts, out);
}

// Round 9
// 260.799 us; speedup vs baseline: 1.8335x; 1.8335x over previous
//
#include <hip/hip_runtime.h>
#include <cfloat>

// Problem constants
#define B_   16
#define C_   256
#define HW_  4096      // 64*64
#define N_   65536     // B_*HW_
#define K_   1024

// Output layout (float32, concatenated flat in return order):
//  [0] loss | [1,+16777216) quantized (b c h w) | [16777217] perplexity
//  [16777218,+67108864) encodings (N,K)
#define OUT_QOFF   1
#define OUT_POFF   16777217
#define OUT_EOFF   16777218

typedef __bf16 bf16x8 __attribute__((ext_vector_type(8)));
typedef float  f32x4  __attribute__((ext_vector_type(4)));

// ---------------------------------------------------------------- bf16 split
__device__ inline ushort f2bf(float f) {
    union { float f; unsigned u; } a; a.f = f;
    unsigned u = a.u;
    unsigned r = (u + 0x7fffu + ((u >> 16) & 1u)) >> 16;   // RNE
    return (ushort)r;
}
__device__ inline float bf2f(ushort u) {
    union { float f; unsigned u; } a; a.u = ((unsigned)u) << 16; return a.f;
}

// ------------------------------------- prep: pack e (2-split) + enorm + cnt0
// One block per code k; thread c handles channel c.
// Packed layout per step s in [0,64): s = (k>>5)*2 + (c>>7); within 16384-B
// block: [split(2)][cg(16)][code(32)][ci(8)] bf16.
__global__ __launch_bounds__(256) void k_prep(const float* __restrict__ emb,
                                              char* __restrict__ epk,
                                              float* __restrict__ enorm,
                                              int* __restrict__ counts) {
    const int k = blockIdx.x;
    const int c = threadIdx.x;
    float v = emb[k * C_ + c];
    ushort h = f2bf(v);
    ushort m = f2bf(v - bf2f(h));
    int s  = (k >> 5) * 2 + (c >> 7);
    int cl = c & 127;
    size_t off = (size_t)s * 16384 + (size_t)((cl >> 3) * 512 + (k & 31) * 16 + (cl & 7) * 2);
    *(ushort*)(epk + off)        = h;
    *(ushort*)(epk + off + 8192) = m;
    float sq = v * v;
    __shared__ float red[4];
#pragma unroll
    for (int o = 32; o > 0; o >>= 1) sq += __shfl_down(sq, o);
    if ((c & 63) == 0) red[c >> 6] = sq;
    __syncthreads();
    if (c == 0) {
        enorm[k]  = (red[0] + red[1]) + (red[2] + red[3]);
        counts[k] = 0;
    }
}

// --------------------------------------------------------- MFMA argmin GEMM
// Block: 128 rows x 1024 codes, 4 waves (32 rows each = 2 row-frags of 16).
// A (2 bf16 splits) in registers; B (2 splits) in a 4-deep LDS multibuffer
// staged by global_load_lds. ONE raw s_barrier per step; counted vmcnt
// (12 steady, 8/4/0 tail) so prefetch loads stay in flight across barriers.
// 4-product fp32 emulation: ah*Bh, ah*Bm, am*Bh, am*Bm (identical to R6).
__global__ __launch_bounds__(256, 2) void k_argmin_mfma(const float* __restrict__ x,
                                                        const char* __restrict__ epk,
                                                        const float* __restrict__ enorm,
                                                        int* __restrict__ bestIdx,
                                                        int* __restrict__ counts) {
    __shared__ __align__(16) char Bs[4][16384];
    __shared__ float En[K_];

    const int tid  = threadIdx.x;
    const int lane = tid & 63;
    const int wid  = tid >> 6;
    const int l15  = lane & 15;
    const int kg   = lane >> 4;
    const int row0 = blockIdx.x * 128;
    const int cpOff = wid * 4096 + lane * 16;   // wave's copy share (4KB of 16KB)
    char* const bsBase = &Bs[0][0];

    for (int i = tid; i < K_; i += 256) En[i] = enorm[i];

    // ---- A fragments: frag f rows = wid*32+f*16+l15, k-elems = kg*8+i
    union FU { bf16x8 v; ushort u[8]; };
    FU Ah[2][8], Am[2][8];
#pragma unroll
    for (int f = 0; f < 2; ++f) {
        const int n  = row0 + wid * 32 + f * 16 + l15;
        const int b  = n >> 12, hw = n & 4095;
        const float* xb = x + (size_t)b * (C_ * HW_) + hw;
#pragma unroll
        for (int cb = 0; cb < 8; ++cb) {
#pragma unroll
            for (int i = 0; i < 8; ++i) {
                float v = xb[(cb * 32 + kg * 8 + i) * HW_];
                ushort h = f2bf(v);
                ushort m = f2bf(v - bf2f(h));
                Ah[f][cb].u[i] = h; Am[f][cb].u[i] = m;
            }
        }
    }

// stage step sn into buffer sn&3 (4 x 16B per thread; src/dst same offset)
#define STAGEI(sn) do {                                                             \
    const char* src_ = epk + (size_t)(sn) * 16384 + (size_t)cpOff;                  \
    char* dst_ = bsBase + (((sn) & 3) * 16384) + cpOff;                             \
    _Pragma("unroll")                                                               \
    for (int j = 0; j < 4; ++j) {                                                   \
        __builtin_amdgcn_global_load_lds(                                           \
            (const __attribute__((address_space(1))) void*)(src_ + j * 1024),       \
            (__attribute__((address_space(3))) void*)(dst_ + j * 1024), 16, 0, 0);  \
    }                                                                               \
} while (0)

    __syncthreads();           // En + A done; clean slate
    STAGEI(0); STAGEI(1); STAGEI(2);   // 3-deep prologue (12 loads in flight)

    float best[2][4] = {{FLT_MAX, FLT_MAX, FLT_MAX, FLT_MAX},
                        {FLT_MAX, FLT_MAX, FLT_MAX, FLT_MAX}};
    int   bidx[2][4] = {{0,0,0,0},{0,0,0,0}};
    const int laneB = kg * 512 + l15 * 16;
    const f32x4 zero = {0.f, 0.f, 0.f, 0.f};
    f32x4 accA0, accB0, accA1, accB1;

// one step: barrier -> (stage s+3) -> counted vmcnt -> ds_read+MFMA cluster
#define STEPX(H, S, DOSTAGE, VMS) do {                                              \
    asm volatile("" ::: "memory");                                                  \
    __builtin_amdgcn_s_barrier();                                                   \
    if (DOSTAGE) STAGEI((S) + 3);                                                   \
    asm volatile("s_waitcnt vmcnt(" VMS ")" ::: "memory");                          \
    {                                                                               \
        const char* bbase = bsBase + (((S) & 3) * 16384) + laneB;                   \
        __builtin_amdgcn_s_setprio(1);                                              \
        _Pragma("unroll")                                                           \
        for (int cbl = 0; cbl < 4; ++cbl) {                                         \
            const char* bp = bbase + cbl * 2048;                                    \
            bf16x8 Bh0 = *(const bf16x8*)(bp);                                      \
            bf16x8 Bm0 = *(const bf16x8*)(bp + 8192);                               \
            bf16x8 Bh1 = *(const bf16x8*)(bp + 256);                                \
            bf16x8 Bm1 = *(const bf16x8*)(bp + 8448);                               \
            const bf16x8 a0h = Ah[0][(H) * 4 + cbl].v;                              \
            const bf16x8 a0m = Am[0][(H) * 4 + cbl].v;                              \
            const bf16x8 a1h = Ah[1][(H) * 4 + cbl].v;                              \
            const bf16x8 a1m = Am[1][(H) * 4 + cbl].v;                              \
            accA0 = __builtin_amdgcn_mfma_f32_16x16x32_bf16(a0h, Bh0, accA0, 0,0,0);\
            accB0 = __builtin_amdgcn_mfma_f32_16x16x32_bf16(a0h, Bh1, accB0, 0,0,0);\
            accA1 = __builtin_amdgcn_mfma_f32_16x16x32_bf16(a1h, Bh0, accA1, 0,0,0);\
            accB1 = __builtin_amdgcn_mfma_f32_16x16x32_bf16(a1h, Bh1, accB1, 0,0,0);\
            accA0 = __builtin_amdgcn_mfma_f32_16x16x32_bf16(a0m, Bh0, accA0, 0,0,0);\
            accB0 = __builtin_amdgcn_mfma_f32_16x16x32_bf16(a0m, Bh1, accB0, 0,0,0);\
            accA1 = __builtin_amdgcn_mfma_f32_16x16x32_bf16(a1m, Bh0, accA1, 0,0,0);\
            accB1 = __builtin_amdgcn_mfma_f32_16x16x32_bf16(a1m, Bh1, accB1, 0,0,0);\
            accA0 = __builtin_amdgcn_mfma_f32_16x16x32_bf16(a0h, Bm0, accA0, 0,0,0);\
            accB0 = __builtin_amdgcn_mfma_f32_16x16x32_bf16(a0h, Bm1, accB0, 0,0,0);\
            accA1 = __builtin_amdgcn_mfma_f32_16x16x32_bf16(a1h, Bm0, accA1, 0,0,0);\
            accB1 = __builtin_amdgcn_mfma_f32_16x16x32_bf16(a1h, Bm1, accB1, 0,0,0);\
            accA0 = __builtin_amdgcn_mfma_f32_16x16x32_bf16(a0m, Bm0, accA0, 0,0,0);\
            accB0 = __builtin_amdgcn_mfma_f32_16x16x32_bf16(a0m, Bm1, accB0, 0,0,0);\
            accA1 = __builtin_amdgcn_mfma_f32_16x16x32_bf16(a1m, Bm0, accA1, 0,0,0);\
            accB1 = __builtin_amdgcn_mfma_f32_16x16x32_bf16(a1m, Bm1, accB1, 0,0,0);\
        }                                                                           \
        __builtin_amdgcn_s_setprio(0);                                              \
    }                                                                               \
} while (0)

// fold: lane holds cols cA = kt*32+l15 (tile0), cB = cA+16 (tile1);
// frag f rows = f*16 + kg*4 + r. Ascending k + strict < => first-occurrence.
#define FOLD(KT) do {                                                               \
    const int cA = (KT) * 32 + l15;                                                 \
    const int cB = cA + 16;                                                         \
    const float enA = En[cA], enB = En[cB];                                         \
    _Pragma("unroll")                                                               \
    for (int r = 0; r < 4; ++r) {                                                   \
        float dA0 = enA - 2.0f * accA0[r];                                          \
        if (dA0 < best[0][r]) { best[0][r] = dA0; bidx[0][r] = cA; }                \
        float dB0 = enB - 2.0f * accB0[r];                                          \
        if (dB0 < best[0][r]) { best[0][r] = dB0; bidx[0][r] = cB; }                \
        float dA1 = enA - 2.0f * accA1[r];                                          \
        if (dA1 < best[1][r]) { best[1][r] = dA1; bidx[1][r] = cA; }                \
        float dB1 = enB - 2.0f * accB1[r];                                          \
        if (dB1 < best[1][r]) { best[1][r] = dB1; bidx[1][r] = cB; }                \
    }                                                                               \
} while (0)

    for (int kt = 0; kt < 30; ++kt) {
        accA0 = zero; accB0 = zero; accA1 = zero; accB1 = zero;
        STEPX(0, 2 * kt,     true, "12");
        STEPX(1, 2 * kt + 1, true, "12");
        FOLD(kt);
    }
    {   // kt = 30: steps 60 (stage 63), 61 (no stage)
        accA0 = zero; accB0 = zero; accA1 = zero; accB1 = zero;
        STEPX(0, 60, true,  "12");
        STEPX(1, 61, false, "8");
        FOLD(30);
    }
    {   // kt = 31: steps 62, 63 (no stages; drain)
        accA0 = zero; accB0 = zero; accA1 = zero; accB1 = zero;
        STEPX(0, 62, false, "4");
        STEPX(1, 63, false, "0");
        FOLD(31);
    }
#undef STEPX
#undef STAGEI
#undef FOLD

    // cross-lane argmin over the 16 cols (lanes sharing kg group)
#pragma unroll
    for (int f = 0; f < 2; ++f) {
#pragma unroll
        for (int r = 0; r < 4; ++r) {
            float v  = best[f][r];
            int   id = bidx[f][r];
#pragma unroll
            for (int m = 1; m < 16; m <<= 1) {
                float ov = __shfl_xor(v, m);
                int   oi = __shfl_xor(id, m);
                if (ov < v || (ov == v && oi < id)) { v = ov; id = oi; }
            }
            if (l15 == 0) {
                int n = row0 + wid * 32 + f * 16 + kg * 4 + r;
                bestIdx[n] = id;
                atomicAdd(&counts[id], 1);
            }
        }
    }
}

// --------------------------------------------- gather quantized + loss part
__global__ __launch_bounds__(256) void k_quant(const float* __restrict__ x,
                                               const float* __restrict__ emb,
                                               const int* __restrict__ bestIdx,
                                               float* __restrict__ outq,
                                               float* __restrict__ partials) {
    const int tid = threadIdx.x;
    float lsum = 0.f;
#pragma unroll
    for (int it = 0; it < 4; ++it) {
        int q  = blockIdx.x * 256 + tid + it * (4096 * 256);
        int f  = q << 2;
        int hw = f & 4095;
        int c  = (f >> 12) & 255;
        int b  = f >> 20;
        int n0 = (b << 12) + hw;
        int4  id = *(const int4*)&bestIdx[n0];
        float4 xv = *(const float4*)&x[f];
        float q0 = emb[id.x * C_ + c];
        float q1 = emb[id.y * C_ + c];
        float q2 = emb[id.z * C_ + c];
        float q3 = emb[id.w * C_ + c];
        f32x4 ov;
        ov.x = xv.x + (q0 - xv.x);
        ov.y = xv.y + (q1 - xv.y);
        ov.z = xv.z + (q2 - xv.z);
        ov.w = xv.w + (q3 - xv.w);
        __builtin_nontemporal_store(ov, (f32x4*)&outq[f]);
        float d0 = q0 - xv.x, d1 = q1 - xv.y, d2 = q2 - xv.z, d3 = q3 - xv.w;
        lsum += d0 * d0 + d1 * d1 + d2 * d2 + d3 * d3;
    }
    __shared__ float red[4];
#pragma unroll
    for (int o = 32; o > 0; o >>= 1) lsum += __shfl_down(lsum, o);
    if ((tid & 63) == 0) red[tid >> 6] = lsum;
    __syncthreads();
    if (tid == 0) partials[blockIdx.x] = (red[0] + red[1]) + (red[2] + red[3]);
}

// ------------------------------------------------------- one-hot encodings
__global__ __launch_bounds__(256) void k_enc(const int* __restrict__ bestIdx,
                                             float* __restrict__ enc) {
    const int k4 = threadIdx.x * 4;
    int row = blockIdx.x * 8;
#pragma unroll
    for (int j = 0; j < 8; ++j, ++row) {
        int idv = bestIdx[row];
        f32x4 v;
        v.x = (k4 + 0 == idv) ? 1.0f : 0.0f;
        v.y = (k4 + 1 == idv) ? 1.0f : 0.0f;
        v.z = (k4 + 2 == idv) ? 1.0f : 0.0f;
        v.w = (k4 + 3 == idv) ? 1.0f : 0.0f;
        __builtin_nontemporal_store(v, (f32x4*)&enc[(size_t)row * K_ + k4]);
    }
}

// ----------------------------------------------------------------- finalize
__global__ __launch_bounds__(256) void k_final(const float* __restrict__ partials,
                                               const int* __restrict__ counts,
                                               float* __restrict__ out) {
    const int tid = threadIdx.x;
    float s = 0.f;
    for (int i = tid; i < 4096; i += 256) s += partials[i];
    float h = 0.f;
    for (int k = tid; k < K_; k += 256) {
        float p = (float)counts[k] * (1.0f / 65536.0f);
        h += p * logf(p + 1e-10f);
    }
    __shared__ float redS[4], redH[4];
#pragma unroll
    for (int o = 32; o > 0; o >>= 1) {
        s += __shfl_down(s, o);
        h += __shfl_down(h, o);
    }
    if ((tid & 63) == 0) { redS[tid >> 6] = s; redH[tid >> 6] = h; }
    __syncthreads();
    if (tid == 0) {
        float S = (redS[0] + redS[1]) + (redS[2] + redS[3]);
        float H = (redH[0] + redH[1]) + (redH[2] + redH[3]);
        out[0]        = 0.25f * S / 16777216.0f;
        out[OUT_POFF] = expf(-H);
    }
}

extern "C" void kernel_launch(void* const* d_in, const int* in_sizes, int n_in,
                              void* d_out, int out_size, void* d_ws, size_t ws_size,
                              hipStream_t stream) {
    const float* x   = (const float*)d_in[0];
    const float* emb = (const float*)d_in[1];
    float* out = (float*)d_out;
    char*  ws  = (char*)d_ws;

    // Workspace layout
    int*   bestIdx  = (int*)(ws);                 // 262144 B
    int*   counts   = (int*)(ws + 262144);        //   4096 B
    float* partials = (float*)(ws + 266240);      //  16384 B
    float* enorm    = (float*)(ws + 282624);      //   4096 B
    char*  epk      = ws + 286720;                // 1048576 B packed e-splits (2-way)

    k_prep       <<<K_,       256, 0, stream>>>(emb, epk, enorm, counts);
    k_argmin_mfma<<<N_ / 128, 256, 0, stream>>>(x, epk, enorm, bestIdx, counts);
    k_quant      <<<4096,     256, 0, stream>>>(x, emb, bestIdx, out + OUT_QOFF, partials);
    k_enc        <<<8192,     256, 0, stream>>>(bestIdx, out + OUT_EOFF);
    k_final      <<<1,        256, 0, stream>>>(partials, counts, out);
}